// Round 1
// baseline (211.432 us; speedup 1.0000x reference)
//
#include <hip/hip_runtime.h>
#include <hip/hip_bf16.h>
#include <stdint.h>

typedef __attribute__((ext_vector_type(4))) float f32x4;
typedef __attribute__((ext_vector_type(8))) __bf16 bf16x8;

#define AS1 __attribute__((address_space(1)))
#define AS3 __attribute__((address_space(3)))

__device__ __forceinline__ ushort f2bf(float f) {
  uint32_t u = __builtin_bit_cast(uint32_t, f);
  u += 0x7fffu + ((u >> 16) & 1u);
  return (ushort)(u >> 16);
}
__device__ __forceinline__ float bf2f(ushort h) {
  uint32_t u = ((uint32_t)h) << 16;
  return __builtin_bit_cast(float, u);
}

// ---------------- elementwise converts ----------------

__global__ void k_cvt_x(const float* __restrict__ x, ushort* __restrict__ xb, int n4) {
  int i = blockIdx.x * blockDim.x + threadIdx.x;
  if (i >= n4) return;
  float4 v = ((const float4*)x)[i];
  ushort4 o;
  o.x = f2bf(v.x); o.y = f2bf(v.y); o.z = f2bf(v.z); o.w = f2bf(v.w);
  ((ushort4*)xb)[i] = o;
}

// src [K][N] fp32 -> dst [N][K] bf16   (K=N=1024)
__global__ void k_transpose_bf(const float* __restrict__ src, ushort* __restrict__ dst,
                               int K, int N) {
  __shared__ float tile[32][33];
  int k0 = blockIdx.y * 32, n0 = blockIdx.x * 32;
  int tx = threadIdx.x, ty = threadIdx.y;  // (32,8)
#pragma unroll
  for (int i = 0; i < 4; i++) tile[ty + i * 8][tx] = src[(size_t)(k0 + ty + i * 8) * N + n0 + tx];
  __syncthreads();
#pragma unroll
  for (int i = 0; i < 4; i++)
    dst[(size_t)(n0 + ty + i * 8) * K + k0 + tx] = f2bf(tile[tx][ty + i * 8]);
}

// ---------------- 128x128 bf16 MFMA GEMM, Bt = [N][K] ----------------
// MODE 0: bf16 out + 3-range bias (QKV).  MODE 1: f32 out + single bias.
template <int MODE>
__global__ __launch_bounds__(256) void k_gemm(const ushort* __restrict__ A,
                                              const ushort* __restrict__ Bt,
                                              void* __restrict__ Cv,
                                              const float* __restrict__ b0,
                                              const float* __restrict__ b1,
                                              const float* __restrict__ b2,
                                              int M, int N, int K, int ldc) {
  __shared__ ushort As[128 * 32];
  __shared__ ushort Bs[128 * 32];
  const int tid = threadIdx.x;
  const int lane = tid & 63;
  const int wid = tid >> 6;
  const int wr = wid >> 1, wc = wid & 1;
  const int row0 = blockIdx.y * 128;
  const int col0 = blockIdx.x * 128;
  const int l15 = lane & 15, l4 = lane >> 4;

  f32x4 acc[4][4] = {};

  for (int k0 = 0; k0 < K; k0 += 32) {
    __syncthreads();
#pragma unroll
    for (int i = 0; i < 2; i++) {
      int c = i * 256 + tid;
      int r = c >> 2, cb = c & 3;
      const ushort* ga = A + (size_t)(row0 + r) * K + k0 + cb * 8;
      __builtin_amdgcn_global_load_lds((const AS1 uint32_t*)ga,
                                       (AS3 uint32_t*)((char*)As + c * 16), 16, 0, 0);
      const ushort* gb = Bt + (size_t)(col0 + r) * K + k0 + cb * 8;
      __builtin_amdgcn_global_load_lds((const AS1 uint32_t*)gb,
                                       (AS3 uint32_t*)((char*)Bs + c * 16), 16, 0, 0);
    }
    __syncthreads();
    bf16x8 av[4], bv[4];
#pragma unroll
    for (int m = 0; m < 4; m++)
      av[m] = *(const bf16x8*)(As + (wr * 64 + m * 16 + l15) * 32 + l4 * 8);
#pragma unroll
    for (int n = 0; n < 4; n++)
      bv[n] = *(const bf16x8*)(Bs + (wc * 64 + n * 16 + l15) * 32 + l4 * 8);
#pragma unroll
    for (int m = 0; m < 4; m++)
#pragma unroll
      for (int n = 0; n < 4; n++)
        acc[m][n] = __builtin_amdgcn_mfma_f32_16x16x32_bf16(av[m], bv[n], acc[m][n], 0, 0, 0);
  }

#pragma unroll
  for (int m = 0; m < 4; m++)
#pragma unroll
    for (int n = 0; n < 4; n++) {
      int colg = col0 + wc * 64 + n * 16 + l15;
      float bias;
      if (MODE == 0) {
        bias = (colg < 1024) ? b0[colg] : ((colg < 2048) ? b1[colg - 1024] : b2[colg - 2048]);
      } else {
        bias = b0[colg];
      }
#pragma unroll
      for (int j = 0; j < 4; j++) {
        int rowg = row0 + wr * 64 + m * 16 + l4 * 4 + j;
        float v = acc[m][n][j] + bias;
        if (MODE == 0)
          ((ushort*)Cv)[(size_t)rowg * ldc + colg] = f2bf(v);
        else
          ((float*)Cv)[(size_t)rowg * ldc + colg] = v;
      }
    }
}

// ---------------- attention stats + colsum ----------------
// scores[tk][tq] = K_h Q_h^T / 8 ; softmax over tq per tk row; colsum over tk.
// grid: (tkb 0..15, bh 0..31). block 256 = 4 waves; wave w owns tk rows w*32..w*32+31.
__global__ __launch_bounds__(256) void k_attn(const ushort* __restrict__ QKV,
                                              float* __restrict__ partial) {
  const int tkb = blockIdx.x, bh = blockIdx.y;
  const int b = bh >> 4, h = bh & 15;
  const int tid = threadIdx.x, lane = tid & 63, w = tid >> 6;
  const int l15 = lane & 15, l4 = lane >> 4;

  __shared__ ushort Ks[128 * 64];
  __shared__ ushort Qs[128 * 64];
  __shared__ float colred[4][128];

  const size_t rs = 3072;
  const ushort* Kbase = QKV + (size_t)(b * 2048 + tkb * 128) * rs + 1024 + h * 64;
  const ushort* Qbase = QKV + (size_t)(b * 2048) * rs + h * 64;

  // stage K tile (swizzled)
#pragma unroll
  for (int i = 0; i < 4; i++) {
    int c = i * 256 + tid;
    int r = c >> 3, cb = c & 7;
    uint4 v = *(const uint4*)(Kbase + (size_t)r * rs + cb * 8);
    int byte = (r * 128 + cb * 16) ^ ((r & 7) << 4);
    *(uint4*)((char*)Ks + byte) = v;
  }
  __syncthreads();

  bf16x8 kf[2][2];
#pragma unroll
  for (int m = 0; m < 2; m++)
#pragma unroll
    for (int d = 0; d < 2; d++) {
      int r = w * 32 + m * 16 + l15;
      int byte = (r * 128 + d * 64 + l4 * 16) ^ ((r & 7) << 4);
      kf[m][d] = *(const bf16x8*)((const char*)Ks + byte);
    }

  float rowm[2][4], rowz[2][4];
#pragma unroll
  for (int m = 0; m < 2; m++)
#pragma unroll
    for (int j = 0; j < 4; j++) { rowm[m][j] = -1e30f; rowz[m][j] = 0.f; }

  const float SC = 0.125f * 1.44269504088896f;  // /sqrt(64), exp2 domain

  for (int pass = 0; pass < 2; ++pass) {
    float rrz[2][4];
    if (pass == 1) {
#pragma unroll
      for (int m = 0; m < 2; m++)
#pragma unroll
        for (int j = 0; j < 4; j++) rrz[m][j] = 1.0f / rowz[m][j];
    }
    for (int tile = 0; tile < 16; ++tile) {
      __syncthreads();
#pragma unroll
      for (int i = 0; i < 4; i++) {
        int c = i * 256 + tid;
        int r = c >> 3, cb = c & 7;
        uint4 v = *(const uint4*)(Qbase + (size_t)(tile * 128 + r) * rs + cb * 8);
        int byte = (r * 128 + cb * 16) ^ ((r & 7) << 4);
        *(uint4*)((char*)Qs + byte) = v;
      }
      __syncthreads();

      f32x4 acc[2][8] = {};
#pragma unroll
      for (int d = 0; d < 2; d++)
#pragma unroll
        for (int n = 0; n < 8; n++) {
          int r = n * 16 + l15;
          int byte = (r * 128 + d * 64 + l4 * 16) ^ ((r & 7) << 4);
          bf16x8 qf = *(const bf16x8*)((const char*)Qs + byte);
#pragma unroll
          for (int m = 0; m < 2; m++)
            acc[m][n] = __builtin_amdgcn_mfma_f32_16x16x32_bf16(kf[m][d], qf, acc[m][n], 0, 0, 0);
        }

      if (pass == 0) {
#pragma unroll
        for (int m = 0; m < 2; m++)
#pragma unroll
          for (int j = 0; j < 4; j++) {
            float tmax = acc[m][0][j];
#pragma unroll
            for (int n = 1; n < 8; n++) tmax = fmaxf(tmax, acc[m][n][j]);
#pragma unroll
            for (int msk = 1; msk < 16; msk <<= 1)
              tmax = fmaxf(tmax, __shfl_xor(tmax, msk, 64));
            float nm = fmaxf(rowm[m][j], tmax * SC);
            float s = 0.f;
#pragma unroll
            for (int n = 0; n < 8; n++) s += exp2f(acc[m][n][j] * SC - nm);
#pragma unroll
            for (int msk = 1; msk < 16; msk <<= 1) s += __shfl_xor(s, msk, 64);
            rowz[m][j] = rowz[m][j] * exp2f(rowm[m][j] - nm) + s;
            rowm[m][j] = nm;
          }
      } else {
        float ca[8];
#pragma unroll
        for (int n = 0; n < 8; n++) ca[n] = 0.f;
#pragma unroll
        for (int m = 0; m < 2; m++)
#pragma unroll
          for (int n = 0; n < 8; n++)
#pragma unroll
            for (int j = 0; j < 4; j++)
              ca[n] += exp2f(acc[m][n][j] * SC - rowm[m][j]) * rrz[m][j];
#pragma unroll
        for (int n = 0; n < 8; n++) {
          float s = ca[n];
          s += __shfl_xor(s, 16, 64);
          s += __shfl_xor(s, 32, 64);
          ca[n] = s;
        }
        if (lane < 16) {
#pragma unroll
          for (int n = 0; n < 8; n++) colred[w][n * 16 + lane] = ca[n];
        }
        __syncthreads();
        if (tid < 128) {
          float s = colred[0][tid] + colred[1][tid] + colred[2][tid] + colred[3][tid];
          partial[((size_t)tkb * 32 + bh) * 2048 + tile * 128 + tid] = s;
        }
      }
    }
  }
}

__global__ void k_reduce_colsum(const float* __restrict__ partial, float* __restrict__ colsum) {
  int g = blockIdx.x * 256 + threadIdx.x;  // 0..65535
  float s = 0.f;
#pragma unroll
  for (int t = 0; t < 16; t++) s += partial[(size_t)t * 65536 + g];
  colsum[g] = s;
}

__global__ void k_mixed(const ushort* __restrict__ QKV, const float* __restrict__ colsum,
                        ushort* __restrict__ mixed) {
  int i = blockIdx.x * 256 + threadIdx.x;  // one per 8 elems; 524288 total
  int row = i >> 7;
  int col = (i & 127) * 8;
  int b = row >> 11, t = row & 2047, h = col >> 6;
  float cs = colsum[((b << 4) + h) * 2048 + t];
  uint4 raw = *(const uint4*)(QKV + (size_t)row * 3072 + 2048 + col);
  const ushort* pv = (const ushort*)&raw;
  ushort o[8];
#pragma unroll
  for (int k = 0; k < 8; k++) o[k] = f2bf(bf2f(pv[k]) * cs);
  *(uint4*)(mixed + (size_t)row * 1024 + col) = *(uint4*)o;
}

// ---------------- launch ----------------

extern "C" void kernel_launch(void* const* d_in, const int* in_sizes, int n_in,
                              void* d_out, int out_size, void* d_ws, size_t ws_size,
                              hipStream_t stream) {
  const float* x = (const float*)d_in[0];
  const float* Wq = (const float*)d_in[1];
  const float* bq = (const float*)d_in[2];
  const float* Wk = (const float*)d_in[3];
  const float* bk = (const float*)d_in[4];
  const float* Wv = (const float*)d_in[5];
  const float* bv = (const float*)d_in[6];
  const float* Wo = (const float*)d_in[7];
  const float* bo = (const float*)d_in[8];

  char* ws = (char*)d_ws;
  ushort* xb   = (ushort*)(ws);                    // 4096x1024 bf16   (8 MB)
  ushort* Wt   = (ushort*)(ws + 8388608);          // 3072x1024 bf16   (6 MB)
  ushort* Wot  = (ushort*)(ws + 14680064);         // 1024x1024 bf16   (2 MB)
  ushort* QKV  = (ushort*)(ws + 16777216);         // 4096x3072 bf16   (24 MB)
  float* partial = (float*)(ws + 41943040);        // 16x32x2048 f32   (4 MB)
  float* colsum  = (float*)(ws + 46137344);        // 32x2048 f32      (256 KB)
  ushort* mixed  = (ushort*)(ws + 46399488);       // 4096x1024 bf16   (8 MB)

  k_cvt_x<<<4096, 256, 0, stream>>>(x, xb, 4096 * 1024 / 4);
  dim3 tb(32, 8);
  k_transpose_bf<<<dim3(32, 32), tb, 0, stream>>>(Wq, Wt, 1024, 1024);
  k_transpose_bf<<<dim3(32, 32), tb, 0, stream>>>(Wk, Wt + 1024 * 1024, 1024, 1024);
  k_transpose_bf<<<dim3(32, 32), tb, 0, stream>>>(Wv, Wt + 2 * 1024 * 1024, 1024, 1024);
  k_transpose_bf<<<dim3(32, 32), tb, 0, stream>>>(Wo, Wot, 1024, 1024);

  k_gemm<0><<<dim3(24, 32), 256, 0, stream>>>(xb, Wt, QKV, bq, bk, bv, 4096, 3072, 1024, 3072);
  k_attn<<<dim3(16, 32), 256, 0, stream>>>(QKV, partial);
  k_reduce_colsum<<<256, 256, 0, stream>>>(partial, colsum);
  k_mixed<<<2048, 256, 0, stream>>>(QKV, colsum, mixed);
  k_gemm<1><<<dim3(8, 32), 256, 0, stream>>>(mixed, Wot, d_out, bo, nullptr, nullptr,
                                             4096, 1024, 1024, 1024);
}

// Round 2
// 155.341 us; speedup vs baseline: 1.3611x; 1.3611x over previous
//
#include <hip/hip_runtime.h>
#include <hip/hip_bf16.h>
#include <stdint.h>

typedef __attribute__((ext_vector_type(4))) float f32x4;
typedef __attribute__((ext_vector_type(8))) __bf16 bf16x8;

#define AS1 __attribute__((address_space(1)))
#define AS3 __attribute__((address_space(3)))

#if __has_builtin(__builtin_amdgcn_exp2f)
#define EXP2(x) __builtin_amdgcn_exp2f(x)
#else
#define EXP2(x) exp2f(x)
#endif

__device__ __forceinline__ ushort f2bf(float f) {
  uint32_t u = __builtin_bit_cast(uint32_t, f);
  u += 0x7fffu + ((u >> 16) & 1u);
  return (ushort)(u >> 16);
}
__device__ __forceinline__ float bf2f(ushort h) {
  uint32_t u = ((uint32_t)h) << 16;
  return __builtin_bit_cast(float, u);
}

// SC = (1/sqrt(64)) * log2(e); folded into Wk/bk so MFMA output is the exp2 arg.
#define SCK 0.18033688011112042f

// ---------------- elementwise converts ----------------

__global__ void k_cvt_x(const float* __restrict__ x, ushort* __restrict__ xb, int n4) {
  int i = blockIdx.x * blockDim.x + threadIdx.x;
  if (i >= n4) return;
  float4 v = ((const float4*)x)[i];
  ushort4 o;
  o.x = f2bf(v.x); o.y = f2bf(v.y); o.z = f2bf(v.z); o.w = f2bf(v.w);
  ((ushort4*)xb)[i] = o;
}

// src [K][N] fp32 -> dst [N][K] bf16 with scale   (K=N=1024)
__global__ void k_transpose_bf(const float* __restrict__ src, ushort* __restrict__ dst,
                               int K, int N, float scale) {
  __shared__ float tile[32][33];
  int k0 = blockIdx.y * 32, n0 = blockIdx.x * 32;
  int tx = threadIdx.x, ty = threadIdx.y;  // (32,8)
#pragma unroll
  for (int i = 0; i < 4; i++) tile[ty + i * 8][tx] = src[(size_t)(k0 + ty + i * 8) * N + n0 + tx];
  __syncthreads();
#pragma unroll
  for (int i = 0; i < 4; i++)
    dst[(size_t)(n0 + ty + i * 8) * K + k0 + tx] = f2bf(tile[tx][ty + i * 8] * scale);
}

// ---------------- 128x128 bf16 MFMA GEMM, Bt = [N][K] ----------------
template <int MODE>
__global__ __launch_bounds__(256) void k_gemm(const ushort* __restrict__ A,
                                              const ushort* __restrict__ Bt,
                                              void* __restrict__ Cv,
                                              const float* __restrict__ b0,
                                              const float* __restrict__ b1,
                                              const float* __restrict__ b2,
                                              int M, int N, int K, int ldc) {
  __shared__ ushort As[128 * 32];
  __shared__ ushort Bs[128 * 32];
  const int tid = threadIdx.x;
  const int lane = tid & 63;
  const int wid = tid >> 6;
  const int wr = wid >> 1, wc = wid & 1;
  const int row0 = blockIdx.y * 128;
  const int col0 = blockIdx.x * 128;
  const int l15 = lane & 15, l4 = lane >> 4;

  f32x4 acc[4][4] = {};

  for (int k0 = 0; k0 < K; k0 += 32) {
    __syncthreads();
#pragma unroll
    for (int i = 0; i < 2; i++) {
      int c = i * 256 + tid;
      int r = c >> 2, cb = c & 3;
      const ushort* ga = A + (size_t)(row0 + r) * K + k0 + cb * 8;
      __builtin_amdgcn_global_load_lds((const AS1 uint32_t*)ga,
                                       (AS3 uint32_t*)((char*)As + c * 16), 16, 0, 0);
      const ushort* gb = Bt + (size_t)(col0 + r) * K + k0 + cb * 8;
      __builtin_amdgcn_global_load_lds((const AS1 uint32_t*)gb,
                                       (AS3 uint32_t*)((char*)Bs + c * 16), 16, 0, 0);
    }
    __syncthreads();
    bf16x8 av[4], bv[4];
#pragma unroll
    for (int m = 0; m < 4; m++)
      av[m] = *(const bf16x8*)(As + (wr * 64 + m * 16 + l15) * 32 + l4 * 8);
#pragma unroll
    for (int n = 0; n < 4; n++)
      bv[n] = *(const bf16x8*)(Bs + (wc * 64 + n * 16 + l15) * 32 + l4 * 8);
#pragma unroll
    for (int m = 0; m < 4; m++)
#pragma unroll
      for (int n = 0; n < 4; n++)
        acc[m][n] = __builtin_amdgcn_mfma_f32_16x16x32_bf16(av[m], bv[n], acc[m][n], 0, 0, 0);
  }

#pragma unroll
  for (int m = 0; m < 4; m++)
#pragma unroll
    for (int n = 0; n < 4; n++) {
      int colg = col0 + wc * 64 + n * 16 + l15;
      float bias;
      if (MODE == 0) {
        bias = (colg < 1024) ? b0[colg]
                             : ((colg < 2048) ? b1[colg - 1024] * SCK : b2[colg - 2048]);
      } else {
        bias = b0[colg];
      }
#pragma unroll
      for (int j = 0; j < 4; j++) {
        int rowg = row0 + wr * 64 + m * 16 + l4 * 4 + j;
        float v = acc[m][n][j] + bias;
        if (MODE == 0)
          ((ushort*)Cv)[(size_t)rowg * ldc + colg] = f2bf(v);
        else
          ((float*)Cv)[(size_t)rowg * ldc + colg] = v;
      }
    }
}

// ---------------- attention pass 1: Z[tk] = sum_tq exp2(S*SC) ----------------
// grid (tkb=16, bh=32, s=2); block 256 = 4 waves; wave w owns tk rows w*32..+32.
__global__ __launch_bounds__(256) void k_attn_z(const ushort* __restrict__ QKV,
                                                float* __restrict__ Zpart) {
  const int tkb = blockIdx.x, bh = blockIdx.y, s = blockIdx.z;
  const int b = bh >> 4, h = bh & 15;
  const int tid = threadIdx.x, lane = tid & 63, w = tid >> 6;
  const int l15 = lane & 15, l4 = lane >> 4;
  const size_t rs = 3072;

  __shared__ ushort Ks[128 * 64];
  __shared__ ushort Qs[128 * 64];

  const ushort* Kbase = QKV + (size_t)(b * 2048 + tkb * 128) * rs + 1024 + h * 64;
  const ushort* Qbase = QKV + (size_t)(b * 2048 + s * 1024) * rs + h * 64;
  const ushort* gq[4];
  int ldsoff[4];
#pragma unroll
  for (int i = 0; i < 4; i++) {
    int c = i * 256 + tid;
    int r = c >> 3;
    int cb = ((c & 7) * 16) ^ ((r & 7) << 4);  // pre-swizzled source bytes
    __builtin_amdgcn_global_load_lds((const AS1 uint32_t*)(Kbase + (size_t)r * rs + (cb >> 1)),
                                     (AS3 uint32_t*)((char*)Ks + c * 16), 16, 0, 0);
    gq[i] = Qbase + (size_t)r * rs + (cb >> 1);
    ldsoff[i] = c * 16;
  }
  __syncthreads();

  bf16x8 kf[2][2];
#pragma unroll
  for (int m = 0; m < 2; m++)
#pragma unroll
    for (int d = 0; d < 2; d++) {
      int r = w * 32 + m * 16 + l15;
      int byte = r * 128 + ((d * 64 + l4 * 16) ^ ((r & 7) << 4));
      kf[m][d] = *(const bf16x8*)((const char*)Ks + byte);
    }

  float z[2][4] = {};
  const f32x4 zero4 = {0.f, 0.f, 0.f, 0.f};

  for (int t = 0; t < 8; ++t) {
    __syncthreads();
#pragma unroll
    for (int i = 0; i < 4; i++)
      __builtin_amdgcn_global_load_lds((const AS1 uint32_t*)gq[i],
                                       (AS3 uint32_t*)((char*)Qs + ldsoff[i]), 16, 0, 0);
#pragma unroll
    for (int i = 0; i < 4; i++) gq[i] += 128 * rs;
    __syncthreads();

    f32x4 acc[2][8];
#pragma unroll
    for (int d = 0; d < 2; d++)
#pragma unroll
      for (int n = 0; n < 8; n++) {
        int r = n * 16 + l15;
        int byte = r * 128 + ((d * 64 + l4 * 16) ^ ((r & 7) << 4));
        bf16x8 qf = *(const bf16x8*)((const char*)Qs + byte);
#pragma unroll
        for (int m = 0; m < 2; m++)
          acc[m][n] = __builtin_amdgcn_mfma_f32_16x16x32_bf16(
              kf[m][d], qf, d == 0 ? zero4 : acc[m][n], 0, 0, 0);
      }
#pragma unroll
    for (int m = 0; m < 2; m++)
#pragma unroll
      for (int n = 0; n < 8; n++)
#pragma unroll
        for (int j = 0; j < 4; j++)
          z[m][j] += EXP2(acc[m][n][j]);
  }

#pragma unroll
  for (int m = 0; m < 2; m++)
#pragma unroll
    for (int j = 0; j < 4; j++) {
      float v = z[m][j];
      v += __shfl_xor(v, 1, 64);
      v += __shfl_xor(v, 2, 64);
      v += __shfl_xor(v, 4, 64);
      v += __shfl_xor(v, 8, 64);
      if (l15 == 0)
        Zpart[(size_t)s * 65536 + bh * 2048 + tkb * 128 + w * 32 + m * 16 + l4 * 4 + j] = v;
    }
}

__global__ void k_rz(const float* __restrict__ Zpart, float* __restrict__ rrz) {
  int g = blockIdx.x * 256 + threadIdx.x;
  rrz[g] = 1.0f / (Zpart[g] + Zpart[65536 + g]);
}

// ---------------- attention pass 2: colsum[tq] = sum_tk exp2(S*SC)*rrz[tk] ----
// grid (tqb=16, bh=32, s=2); wave w owns tq rows w*32..+32 of the block's 128.
__global__ __launch_bounds__(256) void k_attn_cs(const ushort* __restrict__ QKV,
                                                 const float* __restrict__ rrz,
                                                 float* __restrict__ csPart) {
  const int tqb = blockIdx.x, bh = blockIdx.y, s = blockIdx.z;
  const int b = bh >> 4, h = bh & 15;
  const int tid = threadIdx.x, lane = tid & 63, w = tid >> 6;
  const int l15 = lane & 15, l4 = lane >> 4;
  const size_t rs = 3072;

  __shared__ ushort Qs[128 * 64];
  __shared__ ushort Ks[128 * 64];

  const ushort* Qbase = QKV + (size_t)(b * 2048 + tqb * 128) * rs + h * 64;
  const ushort* Kbase = QKV + (size_t)(b * 2048 + s * 1024) * rs + 1024 + h * 64;
  const float* rz0 = rrz + bh * 2048 + s * 1024;
  const ushort* gk[4];
  int ldsoff[4];
#pragma unroll
  for (int i = 0; i < 4; i++) {
    int c = i * 256 + tid;
    int r = c >> 3;
    int cb = ((c & 7) * 16) ^ ((r & 7) << 4);
    __builtin_amdgcn_global_load_lds((const AS1 uint32_t*)(Qbase + (size_t)r * rs + (cb >> 1)),
                                     (AS3 uint32_t*)((char*)Qs + c * 16), 16, 0, 0);
    gk[i] = Kbase + (size_t)r * rs + (cb >> 1);
    ldsoff[i] = c * 16;
  }
  __syncthreads();

  bf16x8 qf[2][2];
#pragma unroll
  for (int m = 0; m < 2; m++)
#pragma unroll
    for (int d = 0; d < 2; d++) {
      int r = w * 32 + m * 16 + l15;
      int byte = r * 128 + ((d * 64 + l4 * 16) ^ ((r & 7) << 4));
      qf[m][d] = *(const bf16x8*)((const char*)Qs + byte);
    }

  float cs[2][4] = {};
  const f32x4 zero4 = {0.f, 0.f, 0.f, 0.f};

  for (int t = 0; t < 8; ++t) {
    __syncthreads();
#pragma unroll
    for (int i = 0; i < 4; i++)
      __builtin_amdgcn_global_load_lds((const AS1 uint32_t*)gk[i],
                                       (AS3 uint32_t*)((char*)Ks + ldsoff[i]), 16, 0, 0);
#pragma unroll
    for (int i = 0; i < 4; i++) gk[i] += 128 * rs;

    float rz[8];
#pragma unroll
    for (int n = 0; n < 8; n++) rz[n] = rz0[t * 128 + n * 16 + l15];
    __syncthreads();

    f32x4 acc[2][8];
#pragma unroll
    for (int d = 0; d < 2; d++)
#pragma unroll
      for (int n = 0; n < 8; n++) {
        int r = n * 16 + l15;
        int byte = r * 128 + ((d * 64 + l4 * 16) ^ ((r & 7) << 4));
        bf16x8 kft = *(const bf16x8*)((const char*)Ks + byte);
#pragma unroll
        for (int m = 0; m < 2; m++)
          acc[m][n] = __builtin_amdgcn_mfma_f32_16x16x32_bf16(
              qf[m][d], kft, d == 0 ? zero4 : acc[m][n], 0, 0, 0);
      }
#pragma unroll
    for (int m = 0; m < 2; m++)
#pragma unroll
      for (int n = 0; n < 8; n++)
#pragma unroll
        for (int j = 0; j < 4; j++)
          cs[m][j] = fmaf(EXP2(acc[m][n][j]), rz[n], cs[m][j]);
  }

#pragma unroll
  for (int m = 0; m < 2; m++)
#pragma unroll
    for (int j = 0; j < 4; j++) {
      float v = cs[m][j];
      v += __shfl_xor(v, 1, 64);
      v += __shfl_xor(v, 2, 64);
      v += __shfl_xor(v, 4, 64);
      v += __shfl_xor(v, 8, 64);
      if (l15 == 0)
        csPart[(size_t)s * 65536 + bh * 2048 + tqb * 128 + w * 32 + m * 16 + l4 * 4 + j] = v;
    }
}

__global__ void k_mixed(const ushort* __restrict__ QKV, const float* __restrict__ csPart,
                        ushort* __restrict__ mixed) {
  int i = blockIdx.x * 256 + threadIdx.x;  // one per 8 elems; 524288 total
  int row = i >> 7;
  int col = (i & 127) * 8;
  int b = row >> 11, t = row & 2047, h = col >> 6;
  int g = ((b << 4) + h) * 2048 + t;
  float cs = csPart[g] + csPart[65536 + g];
  uint4 raw = *(const uint4*)(QKV + (size_t)row * 3072 + 2048 + col);
  const ushort* pv = (const ushort*)&raw;
  ushort o[8];
#pragma unroll
  for (int k = 0; k < 8; k++) o[k] = f2bf(bf2f(pv[k]) * cs);
  *(uint4*)(mixed + (size_t)row * 1024 + col) = *(uint4*)o;
}

// ---------------- launch ----------------

extern "C" void kernel_launch(void* const* d_in, const int* in_sizes, int n_in,
                              void* d_out, int out_size, void* d_ws, size_t ws_size,
                              hipStream_t stream) {
  const float* x = (const float*)d_in[0];
  const float* Wq = (const float*)d_in[1];
  const float* bq = (const float*)d_in[2];
  const float* Wk = (const float*)d_in[3];
  const float* bk = (const float*)d_in[4];
  const float* Wv = (const float*)d_in[5];
  const float* bv = (const float*)d_in[6];
  const float* Wo = (const float*)d_in[7];
  const float* bo = (const float*)d_in[8];

  char* ws = (char*)d_ws;
  ushort* xb     = (ushort*)(ws);                  // 4096x1024 bf16   (8 MB)
  ushort* Wt     = (ushort*)(ws + 8388608);        // 3072x1024 bf16   (6 MB)
  ushort* Wot    = (ushort*)(ws + 14680064);       // 1024x1024 bf16   (2 MB)
  ushort* QKV    = (ushort*)(ws + 16777216);       // 4096x3072 bf16   (24 MB)
  float* Zpart   = (float*)(ws + 41943040);        // 2x32x2048 f32    (512 KB)
  float* rrz     = (float*)(ws + 42467328);        // 32x2048 f32      (256 KB)
  float* csPart  = (float*)(ws + 42729472);        // 2x32x2048 f32    (512 KB)
  ushort* mixed  = (ushort*)(ws + 43253760);       // 4096x1024 bf16   (8 MB)

  k_cvt_x<<<4096, 256, 0, stream>>>(x, xb, 4096 * 1024 / 4);
  dim3 tb(32, 8);
  k_transpose_bf<<<dim3(32, 32), tb, 0, stream>>>(Wq, Wt, 1024, 1024, 1.0f);
  k_transpose_bf<<<dim3(32, 32), tb, 0, stream>>>(Wk, Wt + 1024 * 1024, 1024, 1024, SCK);
  k_transpose_bf<<<dim3(32, 32), tb, 0, stream>>>(Wv, Wt + 2 * 1024 * 1024, 1024, 1024, 1.0f);
  k_transpose_bf<<<dim3(32, 32), tb, 0, stream>>>(Wo, Wot, 1024, 1024, 1.0f);

  k_gemm<0><<<dim3(24, 32), 256, 0, stream>>>(xb, Wt, QKV, bq, bk, bv, 4096, 3072, 1024, 3072);
  k_attn_z<<<dim3(16, 32, 2), 256, 0, stream>>>(QKV, Zpart);
  k_rz<<<256, 256, 0, stream>>>(Zpart, rrz);
  k_attn_cs<<<dim3(16, 32, 2), 256, 0, stream>>>(QKV, rrz, csPart);
  k_mixed<<<2048, 256, 0, stream>>>(QKV, csPart, mixed);
  k_gemm<1><<<dim3(8, 32), 256, 0, stream>>>(mixed, Wot, d_out, bo, nullptr, nullptr,
                                             4096, 1024, 1024, 1024);
}

// Round 3
// 145.871 us; speedup vs baseline: 1.4494x; 1.0649x over previous
//
#include <hip/hip_runtime.h>
#include <hip/hip_bf16.h>
#include <stdint.h>

typedef __attribute__((ext_vector_type(4))) float f32x4;
typedef __attribute__((ext_vector_type(8))) __bf16 bf16x8;

#define AS1 __attribute__((address_space(1)))
#define AS3 __attribute__((address_space(3)))

#if __has_builtin(__builtin_amdgcn_exp2f)
#define EXP2(x) __builtin_amdgcn_exp2f(x)
#else
#define EXP2(x) exp2f(x)
#endif

__device__ __forceinline__ ushort f2bf(float f) {
  uint32_t u = __builtin_bit_cast(uint32_t, f);
  u += 0x7fffu + ((u >> 16) & 1u);
  return (ushort)(u >> 16);
}
__device__ __forceinline__ float bf2f(ushort h) {
  uint32_t u = ((uint32_t)h) << 16;
  return __builtin_bit_cast(float, u);
}

// SC = (1/sqrt(64)) * log2(e); folded into Wk/bk so MFMA output is the exp2 arg.
#define SCK 0.18033688011112042f

// ---------------- elementwise converts ----------------

__global__ void k_cvt_x(const float* __restrict__ x, ushort* __restrict__ xb, int n4) {
  int i = blockIdx.x * blockDim.x + threadIdx.x;
  if (i >= n4) return;
  float4 v = ((const float4*)x)[i];
  ushort4 o;
  o.x = f2bf(v.x); o.y = f2bf(v.y); o.z = f2bf(v.z); o.w = f2bf(v.w);
  ((ushort4*)xb)[i] = o;
}

// All four weight transposes in one launch. src [K][N] f32 -> dst [N][K] bf16 * scale.
__global__ void k_prep_w(const float* __restrict__ Wq, const float* __restrict__ Wk,
                         const float* __restrict__ Wv, const float* __restrict__ Wo,
                         ushort* __restrict__ Wt, ushort* __restrict__ Wot) {
  __shared__ float tile[32][33];
  int z = blockIdx.z;
  const float* src = (z == 0) ? Wq : (z == 1) ? Wk : (z == 2) ? Wv : Wo;
  ushort* dst = (z < 3) ? (Wt + (size_t)z * 1048576) : Wot;
  float scale = (z == 1) ? SCK : 1.0f;
  int k0 = blockIdx.y * 32, n0 = blockIdx.x * 32;
  int tx = threadIdx.x, ty = threadIdx.y;  // (32,8)
#pragma unroll
  for (int i = 0; i < 4; i++)
    tile[ty + i * 8][tx] = src[(size_t)(k0 + ty + i * 8) * 1024 + n0 + tx];
  __syncthreads();
#pragma unroll
  for (int i = 0; i < 4; i++)
    dst[(size_t)(n0 + ty + i * 8) * 1024 + k0 + tx] = f2bf(tile[tx][ty + i * 8] * scale);
}

// ---------------- 256x256 counted-vmcnt pipelined GEMM (Bt = [N][K]) ----------------
// BK=32, 4 rotating LDS buffers (A 16KB + B 16KB each), 512 thr = 2x4 waves.
// Per K-tile phase: ds_read frags || stage t+3 -> 32 MFMA (setprio) -> vmcnt(8) -> barrier.
#define GLD(src, dst) \
  __builtin_amdgcn_global_load_lds((const AS1 uint32_t*)(src), (AS3 uint32_t*)(dst), 16, 0, 0)

template <int MODE>
__global__ __launch_bounds__(512, 2) void k_gemm8(const ushort* __restrict__ A,
                                                  const ushort* __restrict__ Bt,
                                                  void* __restrict__ Cv,
                                                  const float* __restrict__ b0,
                                                  const float* __restrict__ b1,
                                                  const float* __restrict__ b2,
                                                  int K, int ldc) {
  __shared__ char ldsb[131072];
  const int tid = threadIdx.x;
  const int lane = tid & 63;
  const int wid = tid >> 6;
  const int wr = wid >> 2, wc = wid & 3;
  const int l15 = lane & 15, l4 = lane >> 4;
  const int row0 = blockIdx.y * 256;
  const int col0 = blockIdx.x * 256;
  const int T = K >> 5;

  // staging source pointers (swizzled slot: sl_g = (c&3) ^ ((c>>3)&3))
  const int swz = ((tid & 3) ^ ((tid >> 3) & 3)) << 3;
  const ushort* Ap = A + (size_t)(row0 + (tid >> 2)) * K + swz;
  const ushort* Bp = Bt + (size_t)(col0 + (tid >> 2)) * K + swz;

#define STAGE(t)                                        \
  do {                                                  \
    char* bufs = ldsb + (((t) & 3) << 15);              \
    const ushort* pa = Ap + (size_t)(t) * 32;           \
    const ushort* pb = Bp + (size_t)(t) * 32;           \
    GLD(pa, bufs + tid * 16);                           \
    GLD(pa + 128 * K, bufs + 8192 + tid * 16);          \
    GLD(pb, bufs + 16384 + tid * 16);                   \
    GLD(pb + 128 * K, bufs + 24576 + tid * 16);         \
  } while (0)

  // per-lane fragment byte offsets within a buffer (read-side swizzle matches write)
  int aoffL[8], boffL[4];
#pragma unroll
  for (int m = 0; m < 8; m++) {
    int r = wr * 128 + m * 16 + l15;
    aoffL[m] = r * 64 + ((l4 ^ ((r >> 1) & 3)) << 4);
  }
#pragma unroll
  for (int n = 0; n < 4; n++) {
    int r = wc * 64 + n * 16 + l15;
    boffL[n] = 16384 + r * 64 + ((l4 ^ ((r >> 1) & 3)) << 4);
  }

  f32x4 acc[8][4] = {};

  STAGE(0);
  STAGE(1);
  STAGE(2);
  asm volatile("s_waitcnt vmcnt(8)" ::: "memory");
  __builtin_amdgcn_sched_barrier(0);
  __builtin_amdgcn_s_barrier();
  __builtin_amdgcn_sched_barrier(0);

#define PHASE(t, DO_STAGE, VMSTR)                                                   \
  do {                                                                              \
    char* buf = ldsb + (((t) & 3) << 15);                                           \
    bf16x8 af[8], bfr[4];                                                           \
    _Pragma("unroll") for (int m = 0; m < 8; m++)                                   \
        af[m] = *(const bf16x8*)(buf + aoffL[m]);                                   \
    _Pragma("unroll") for (int n = 0; n < 4; n++)                                   \
        bfr[n] = *(const bf16x8*)(buf + boffL[n]);                                  \
    if (DO_STAGE) STAGE((t) + 3);                                                   \
    __builtin_amdgcn_s_setprio(1);                                                  \
    _Pragma("unroll") for (int m = 0; m < 8; m++)                                   \
        _Pragma("unroll") for (int n = 0; n < 4; n++)                               \
            acc[m][n] = __builtin_amdgcn_mfma_f32_16x16x32_bf16(af[m], bfr[n],      \
                                                                acc[m][n], 0, 0, 0);\
    __builtin_amdgcn_s_setprio(0);                                                  \
    asm volatile(VMSTR ::: "memory");                                               \
    __builtin_amdgcn_sched_barrier(0);                                              \
    __builtin_amdgcn_s_barrier();                                                   \
    __builtin_amdgcn_sched_barrier(0);                                              \
  } while (0)

  for (int t = 0; t < T - 3; ++t) PHASE(t, true, "s_waitcnt vmcnt(8)");
  PHASE(T - 3, false, "s_waitcnt vmcnt(4)");
  PHASE(T - 2, false, "s_waitcnt vmcnt(0)");
  PHASE(T - 1, false, "s_nop 0");

#undef PHASE
#undef STAGE

#pragma unroll
  for (int m = 0; m < 8; m++)
#pragma unroll
    for (int n = 0; n < 4; n++) {
      int colg = col0 + wc * 64 + n * 16 + l15;
      float bias;
      if (MODE == 0) {
        bias = (colg < 1024) ? b0[colg]
                             : ((colg < 2048) ? b1[colg - 1024] * SCK : b2[colg - 2048]);
      } else {
        bias = b0[colg];
      }
#pragma unroll
      for (int j = 0; j < 4; j++) {
        int rowg = row0 + wr * 128 + m * 16 + l4 * 4 + j;
        float v = acc[m][n][j] + bias;
        if (MODE == 0)
          ((ushort*)Cv)[(size_t)rowg * ldc + colg] = f2bf(v);
        else
          ((float*)Cv)[(size_t)rowg * ldc + colg] = v;
      }
    }
}

// ---------------- 128x128 bf16 MFMA GEMM (2-phase), for the small output GEMM ----
template <int MODE>
__global__ __launch_bounds__(256) void k_gemm(const ushort* __restrict__ A,
                                              const ushort* __restrict__ Bt,
                                              void* __restrict__ Cv,
                                              const float* __restrict__ b0,
                                              int M, int N, int K, int ldc) {
  __shared__ ushort As[128 * 32];
  __shared__ ushort Bs[128 * 32];
  const int tid = threadIdx.x;
  const int lane = tid & 63;
  const int wid = tid >> 6;
  const int wr = wid >> 1, wc = wid & 1;
  const int row0 = blockIdx.y * 128;
  const int col0 = blockIdx.x * 128;
  const int l15 = lane & 15, l4 = lane >> 4;

  f32x4 acc[4][4] = {};

  for (int k0 = 0; k0 < K; k0 += 32) {
    __syncthreads();
#pragma unroll
    for (int i = 0; i < 2; i++) {
      int c = i * 256 + tid;
      int r = c >> 2, cb = c & 3;
      const ushort* ga = A + (size_t)(row0 + r) * K + k0 + cb * 8;
      GLD(ga, (char*)As + c * 16);
      const ushort* gb = Bt + (size_t)(col0 + r) * K + k0 + cb * 8;
      GLD(gb, (char*)Bs + c * 16);
    }
    __syncthreads();
    bf16x8 av[4], bv[4];
#pragma unroll
    for (int m = 0; m < 4; m++)
      av[m] = *(const bf16x8*)(As + (wr * 64 + m * 16 + l15) * 32 + l4 * 8);
#pragma unroll
    for (int n = 0; n < 4; n++)
      bv[n] = *(const bf16x8*)(Bs + (wc * 64 + n * 16 + l15) * 32 + l4 * 8);
#pragma unroll
    for (int m = 0; m < 4; m++)
#pragma unroll
      for (int n = 0; n < 4; n++)
        acc[m][n] = __builtin_amdgcn_mfma_f32_16x16x32_bf16(av[m], bv[n], acc[m][n], 0, 0, 0);
  }

#pragma unroll
  for (int m = 0; m < 4; m++)
#pragma unroll
    for (int n = 0; n < 4; n++) {
      int colg = col0 + wc * 64 + n * 16 + l15;
      float bias = b0[colg];
#pragma unroll
      for (int j = 0; j < 4; j++) {
        int rowg = row0 + wr * 64 + m * 16 + l4 * 4 + j;
        float v = acc[m][n][j] + bias;
        if (MODE == 0)
          ((ushort*)Cv)[(size_t)rowg * ldc + colg] = f2bf(v);
        else
          ((float*)Cv)[(size_t)rowg * ldc + colg] = v;
      }
    }
}

// ---------------- attention pass 1: Z[tk] = sum_tq exp2(S*SC) ----------------
__global__ __launch_bounds__(256) void k_attn_z(const ushort* __restrict__ QKV,
                                                float* __restrict__ Zpart) {
  const int tkb = blockIdx.x, bh = blockIdx.y, s = blockIdx.z;
  const int b = bh >> 4, h = bh & 15;
  const int tid = threadIdx.x, lane = tid & 63, w = tid >> 6;
  const int l15 = lane & 15, l4 = lane >> 4;
  const size_t rs = 3072;

  __shared__ ushort Ks[128 * 64];
  __shared__ ushort Qs[128 * 64];

  const ushort* Kbase = QKV + (size_t)(b * 2048 + tkb * 128) * rs + 1024 + h * 64;
  const ushort* Qbase = QKV + (size_t)(b * 2048 + s * 1024) * rs + h * 64;
  const ushort* gq[4];
  int ldsoff[4];
#pragma unroll
  for (int i = 0; i < 4; i++) {
    int c = i * 256 + tid;
    int r = c >> 3;
    int cb = ((c & 7) * 16) ^ ((r & 7) << 4);
    GLD(Kbase + (size_t)r * rs + (cb >> 1), (char*)Ks + c * 16);
    gq[i] = Qbase + (size_t)r * rs + (cb >> 1);
    ldsoff[i] = c * 16;
  }
  __syncthreads();

  bf16x8 kf[2][2];
#pragma unroll
  for (int m = 0; m < 2; m++)
#pragma unroll
    for (int d = 0; d < 2; d++) {
      int r = w * 32 + m * 16 + l15;
      int byte = r * 128 + ((d * 64 + l4 * 16) ^ ((r & 7) << 4));
      kf[m][d] = *(const bf16x8*)((const char*)Ks + byte);
    }

  float z[2][4] = {};
  const f32x4 zero4 = {0.f, 0.f, 0.f, 0.f};

  for (int t = 0; t < 8; ++t) {
    __syncthreads();
#pragma unroll
    for (int i = 0; i < 4; i++) GLD(gq[i], (char*)Qs + ldsoff[i]);
#pragma unroll
    for (int i = 0; i < 4; i++) gq[i] += 128 * rs;
    __syncthreads();

    f32x4 acc[2][8];
#pragma unroll
    for (int d = 0; d < 2; d++)
#pragma unroll
      for (int n = 0; n < 8; n++) {
        int r = n * 16 + l15;
        int byte = r * 128 + ((d * 64 + l4 * 16) ^ ((r & 7) << 4));
        bf16x8 qf = *(const bf16x8*)((const char*)Qs + byte);
#pragma unroll
        for (int m = 0; m < 2; m++)
          acc[m][n] = __builtin_amdgcn_mfma_f32_16x16x32_bf16(
              kf[m][d], qf, d == 0 ? zero4 : acc[m][n], 0, 0, 0);
      }
#pragma unroll
    for (int m = 0; m < 2; m++)
#pragma unroll
      for (int n = 0; n < 8; n++)
#pragma unroll
        for (int j = 0; j < 4; j++)
          z[m][j] += EXP2(acc[m][n][j]);
  }

#pragma unroll
  for (int m = 0; m < 2; m++)
#pragma unroll
    for (int j = 0; j < 4; j++) {
      float v = z[m][j];
      v += __shfl_xor(v, 1, 64);
      v += __shfl_xor(v, 2, 64);
      v += __shfl_xor(v, 4, 64);
      v += __shfl_xor(v, 8, 64);
      if (l15 == 0)
        Zpart[(size_t)s * 65536 + bh * 2048 + tkb * 128 + w * 32 + m * 16 + l4 * 4 + j] = v;
    }
}

__global__ void k_rz(const float* __restrict__ Zpart, float* __restrict__ rrz) {
  int g = blockIdx.x * 256 + threadIdx.x;
  rrz[g] = 1.0f / (Zpart[g] + Zpart[65536 + g]);
}

// ---------------- attention pass 2: colsum[tq] = sum_tk exp2(S*SC)*rrz[tk] ----
__global__ __launch_bounds__(256) void k_attn_cs(const ushort* __restrict__ QKV,
                                                 const float* __restrict__ rrz,
                                                 float* __restrict__ csPart) {
  const int tqb = blockIdx.x, bh = blockIdx.y, s = blockIdx.z;
  const int b = bh >> 4, h = bh & 15;
  const int tid = threadIdx.x, lane = tid & 63, w = tid >> 6;
  const int l15 = lane & 15, l4 = lane >> 4;
  const size_t rs = 3072;

  __shared__ ushort Qs[128 * 64];
  __shared__ ushort Ks[128 * 64];

  const ushort* Qbase = QKV + (size_t)(b * 2048 + tqb * 128) * rs + h * 64;
  const ushort* Kbase = QKV + (size_t)(b * 2048 + s * 1024) * rs + 1024 + h * 64;
  const float* rz0 = rrz + bh * 2048 + s * 1024;
  const ushort* gk[4];
  int ldsoff[4];
#pragma unroll
  for (int i = 0; i < 4; i++) {
    int c = i * 256 + tid;
    int r = c >> 3;
    int cb = ((c & 7) * 16) ^ ((r & 7) << 4);
    GLD(Qbase + (size_t)r * rs + (cb >> 1), (char*)Qs + c * 16);
    gk[i] = Kbase + (size_t)r * rs + (cb >> 1);
    ldsoff[i] = c * 16;
  }
  __syncthreads();

  bf16x8 qf[2][2];
#pragma unroll
  for (int m = 0; m < 2; m++)
#pragma unroll
    for (int d = 0; d < 2; d++) {
      int r = w * 32 + m * 16 + l15;
      int byte = r * 128 + ((d * 64 + l4 * 16) ^ ((r & 7) << 4));
      qf[m][d] = *(const bf16x8*)((const char*)Qs + byte);
    }

  float cs[2][4] = {};
  const f32x4 zero4 = {0.f, 0.f, 0.f, 0.f};

  for (int t = 0; t < 8; ++t) {
    __syncthreads();
#pragma unroll
    for (int i = 0; i < 4; i++) GLD(gk[i], (char*)Ks + ldsoff[i]);
#pragma unroll
    for (int i = 0; i < 4; i++) gk[i] += 128 * rs;

    float rz[8];
#pragma unroll
    for (int n = 0; n < 8; n++) rz[n] = rz0[t * 128 + n * 16 + l15];
    __syncthreads();

    f32x4 acc[2][8];
#pragma unroll
    for (int d = 0; d < 2; d++)
#pragma unroll
      for (int n = 0; n < 8; n++) {
        int r = n * 16 + l15;
        int byte = r * 128 + ((d * 64 + l4 * 16) ^ ((r & 7) << 4));
        bf16x8 kft = *(const bf16x8*)((const char*)Ks + byte);
#pragma unroll
        for (int m = 0; m < 2; m++)
          acc[m][n] = __builtin_amdgcn_mfma_f32_16x16x32_bf16(
              qf[m][d], kft, d == 0 ? zero4 : acc[m][n], 0, 0, 0);
      }
#pragma unroll
    for (int m = 0; m < 2; m++)
#pragma unroll
      for (int n = 0; n < 8; n++)
#pragma unroll
        for (int j = 0; j < 4; j++)
          cs[m][j] = fmaf(EXP2(acc[m][n][j]), rz[n], cs[m][j]);
  }

#pragma unroll
  for (int m = 0; m < 2; m++)
#pragma unroll
    for (int j = 0; j < 4; j++) {
      float v = cs[m][j];
      v += __shfl_xor(v, 1, 64);
      v += __shfl_xor(v, 2, 64);
      v += __shfl_xor(v, 4, 64);
      v += __shfl_xor(v, 8, 64);
      if (l15 == 0)
        csPart[(size_t)s * 65536 + bh * 2048 + tqb * 128 + w * 32 + m * 16 + l4 * 4 + j] = v;
    }
}

__global__ void k_mixed(const ushort* __restrict__ QKV, const float* __restrict__ csPart,
                        ushort* __restrict__ mixed) {
  int i = blockIdx.x * 256 + threadIdx.x;
  int row = i >> 7;
  int col = (i & 127) * 8;
  int b = row >> 11, t = row & 2047, h = col >> 6;
  int g = ((b << 4) + h) * 2048 + t;
  float cs = csPart[g] + csPart[65536 + g];
  uint4 raw = *(const uint4*)(QKV + (size_t)row * 3072 + 2048 + col);
  const ushort* pv = (const ushort*)&raw;
  ushort o[8];
#pragma unroll
  for (int k = 0; k < 8; k++) o[k] = f2bf(bf2f(pv[k]) * cs);
  *(uint4*)(mixed + (size_t)row * 1024 + col) = *(uint4*)o;
}

// ---------------- launch ----------------

extern "C" void kernel_launch(void* const* d_in, const int* in_sizes, int n_in,
                              void* d_out, int out_size, void* d_ws, size_t ws_size,
                              hipStream_t stream) {
  const float* x = (const float*)d_in[0];
  const float* Wq = (const float*)d_in[1];
  const float* bq = (const float*)d_in[2];
  const float* Wk = (const float*)d_in[3];
  const float* bk = (const float*)d_in[4];
  const float* Wv = (const float*)d_in[5];
  const float* bv = (const float*)d_in[6];
  const float* Wo = (const float*)d_in[7];
  const float* bo = (const float*)d_in[8];

  char* ws = (char*)d_ws;
  ushort* xb     = (ushort*)(ws);                  // 4096x1024 bf16   (8 MB)
  ushort* Wt     = (ushort*)(ws + 8388608);        // 3072x1024 bf16   (6 MB)
  ushort* Wot    = (ushort*)(ws + 14680064);       // 1024x1024 bf16   (2 MB)
  ushort* QKV    = (ushort*)(ws + 16777216);       // 4096x3072 bf16   (24 MB)
  float* Zpart   = (float*)(ws + 41943040);        // 2x32x2048 f32    (512 KB)
  float* rrz     = (float*)(ws + 42467328);        // 32x2048 f32      (256 KB)
  float* csPart  = (float*)(ws + 42729472);        // 2x32x2048 f32    (512 KB)
  ushort* mixed  = (ushort*)(ws + 43253760);       // 4096x1024 bf16   (8 MB)

  k_cvt_x<<<4096, 256, 0, stream>>>(x, xb, 4096 * 1024 / 4);
  k_prep_w<<<dim3(32, 32, 4), dim3(32, 8), 0, stream>>>(Wq, Wk, Wv, Wo, Wt, Wot);

  k_gemm8<0><<<dim3(12, 16), 512, 0, stream>>>(xb, Wt, QKV, bq, bk, bv, 1024, 3072);
  k_attn_z<<<dim3(16, 32, 2), 256, 0, stream>>>(QKV, Zpart);
  k_rz<<<256, 256, 0, stream>>>(Zpart, rrz);
  k_attn_cs<<<dim3(16, 32, 2), 256, 0, stream>>>(QKV, rrz, csPart);
  k_mixed<<<2048, 256, 0, stream>>>(QKV, csPart, mixed);
  k_gemm<1><<<dim3(8, 32), 256, 0, stream>>>(mixed, Wot, d_out, bo, 4096, 1024, 1024, 1024);
}